// Round 15
// baseline (1028.880 us; speedup 1.0000x reference)
//
#include <hip/hip_runtime.h>
#include <hip/hip_bf16.h>

#define B_ 2
#define N_ 16384
#define BN 32768
#define W_ 256
#define NF_ 256
#define E_ 524288
#define L_ 4
#define KS_ 32   // split-K for spectral fwd

typedef __attribute__((ext_vector_type(8))) short bf16x8;
typedef __attribute__((ext_vector_type(4))) float f32x4;

__device__ __forceinline__ unsigned short f2b(float x) {
    __hip_bfloat16 h = __float2bfloat16(x);
    return *reinterpret_cast<unsigned short*>(&h);
}
__device__ __forceinline__ float b2f(unsigned short u) {
    union { unsigned int i; float f; } c; c.i = ((unsigned int)u) << 16; return c.f;
}
__device__ __forceinline__ float geluf(float x) {
    return 0.5f * x * (1.0f + erff(x * 0.70710678118654752440f));
}

// =============== bf16 MFMA NT GEMM (proj / q-head) ===============
// 128x128 tile, 4 waves of 64x64, BK=64, global_load_lds staging with XOR-swizzled LDS.
// OUTM: 0=f32 store, 1=bf16 store. QHEAD: fused relu-dot epilogue. TROUT: also emit C^T via LDS.
template<bool DUAL, int OUTM, bool BIAS, bool QHEAD = false, bool TROUT = false>
__global__ __launch_bounds__(256) void k_mfma_nt(
    const unsigned short* __restrict__ A1, int lda1, long A1o, long A1i,
    const unsigned short* __restrict__ B1, int ldb1, long B1o, long B1i, int K1,
    const unsigned short* __restrict__ A2, int lda2, long A2o,
    const unsigned short* __restrict__ B2, int ldb2, long B2o, int K2,
    void* __restrict__ Cv, int ldc, long Co, long Ci,
    unsigned short* __restrict__ CT,
    const float* __restrict__ bias,
    const float* __restrict__ qw, const float* __restrict__ q2b,
    float* __restrict__ qout, int zdiv)
{
    __shared__ unsigned short lds[16384];
    const int t = threadIdx.x;
    const int wid = t >> 6, lane = t & 63;
    const int wr = wid >> 1, wc = wid & 1;
    const int m0 = blockIdx.y * 128, n0 = blockIdx.x * 128;
    const int z = blockIdx.z;
    const int zo = z / zdiv, zi = z - zo * zdiv;
    A1 += zo * A1o + zi * A1i;
    B1 += zo * B1o + zi * B1i;
    if (DUAL) { A2 += zo * A2o; B2 += zo * B2o; }

    const int srow  = t >> 3;
    const int sgran = (t & 7) ^ (srow & 7);
    const int rlo   = lane & 15;
    const int hi    = lane >> 4;

    f32x4 acc[4][4] = {};

    const int nph = DUAL ? 2 : 1;
    for (int ph = 0; ph < nph; ++ph) {
        const unsigned short* A  = (DUAL && ph) ? A2 : A1;
        const unsigned short* Bp = (DUAL && ph) ? B2 : B1;
        const int lda = (DUAL && ph) ? lda2 : lda1;
        const int ldb = (DUAL && ph) ? ldb2 : ldb1;
        const int K   = (DUAL && ph) ? K2 : K1;
        for (int k0 = 0; k0 < K; k0 += 64) {
            __syncthreads();
            #pragma unroll
            for (int j = 0; j < 4; ++j) {
                const unsigned short* ga = A + (long)(m0 + j*32 + srow) * lda + k0 + sgran*8;
                __builtin_amdgcn_global_load_lds(
                    (const __attribute__((address_space(1))) void*)ga,
                    (__attribute__((address_space(3))) void*)&lds[(j*4 + wid) * 512],
                    16, 0, 0);
            }
            #pragma unroll
            for (int j = 0; j < 4; ++j) {
                const unsigned short* gb = Bp + (long)(n0 + j*32 + srow) * ldb + k0 + sgran*8;
                __builtin_amdgcn_global_load_lds(
                    (const __attribute__((address_space(1))) void*)gb,
                    (__attribute__((address_space(3))) void*)&lds[8192 + (j*4 + wid) * 512],
                    16, 0, 0);
            }
            __syncthreads();
            #pragma unroll
            for (int kk = 0; kk < 2; ++kk) {
                const int g8 = (((kk*4 + hi) ^ (lane & 7)) << 3);
                bf16x8 a[4], b[4];
                #pragma unroll
                for (int fm = 0; fm < 4; ++fm)
                    a[fm] = *(const bf16x8*)&lds[(wr*64 + fm*16 + rlo)*64 + g8];
                #pragma unroll
                for (int fn = 0; fn < 4; ++fn)
                    b[fn] = *(const bf16x8*)&lds[8192 + (wc*64 + fn*16 + rlo)*64 + g8];
                #pragma unroll
                for (int fm = 0; fm < 4; ++fm)
                    #pragma unroll
                    for (int fn = 0; fn < 4; ++fn)
                        acc[fm][fn] = __builtin_amdgcn_mfma_f32_16x16x32_bf16(
                            a[fm], b[fn], acc[fm][fn], 0, 0, 0);
            }
        }
    }

    const int mb = m0 + wr*64, nb = n0 + wc*64;
    if (QHEAD) {
        __syncthreads();
        float* rs = (float*)lds;
        if (t < 128) rs[t] = 0.f;
        __syncthreads();
        #pragma unroll
        for (int fm = 0; fm < 4; ++fm)
            #pragma unroll
            for (int r = 0; r < 4; ++r) {
                const int m_l = wr*64 + fm*16 + hi*4 + r;
                float part = 0.f;
                #pragma unroll
                for (int fn = 0; fn < 4; ++fn) {
                    const int n = nb + fn*16 + rlo;
                    part += fmaxf(acc[fm][fn][r] + bias[n], 0.f) * qw[n];
                }
                #pragma unroll
                for (int o = 8; o; o >>= 1) part += __shfl_xor(part, o);
                if (rlo == 0) atomicAdd(&rs[m_l], part);
            }
        __syncthreads();
        if (t < 128) qout[m0 + t] = rs[t] + q2b[0];
    } else if (OUTM == 1) {
        unsigned short* C = (unsigned short*)Cv + zo * Co + zi * Ci;
        #pragma unroll
        for (int fn = 0; fn < 4; ++fn) {
            const int n = nb + fn*16 + rlo;
            const float bv = BIAS ? bias[n] : 0.f;
            #pragma unroll
            for (int fm = 0; fm < 4; ++fm)
                #pragma unroll
                for (int r = 0; r < 4; ++r) {
                    const int m = mb + fm*16 + hi*4 + r;
                    C[(long)m*ldc + n] = f2b(acc[fm][fn][r] + bv);
                }
        }
        if (TROUT) {
            __syncthreads();
            unsigned short* wlds = &lds[wid * 4096];
            #pragma unroll
            for (int fm = 0; fm < 4; ++fm)
                #pragma unroll
                for (int r = 0; r < 4; ++r) {
                    const int m_l = fm*16 + hi*4 + r;
                    const int sw = (m_l & 7) << 3;
                    #pragma unroll
                    for (int fn = 0; fn < 4; ++fn) {
                        const int n_l = fn*16 + rlo;
                        const float bv = BIAS ? bias[nb + n_l] : 0.f;
                        wlds[m_l*64 + (n_l ^ sw)] = f2b(acc[fm][fn][r] + bv);
                    }
                }
            const int bb = mb >> 14, loc = mb & 16383;
            const int mq = lane & 15, nq = lane >> 4;
            #pragma unroll
            for (int p = 0; p < 16; ++p) {
                const int n_l = p*4 + nq;
                unsigned short v[4];
                #pragma unroll
                for (int j = 0; j < 4; ++j) {
                    const int m_l = mq*4 + j;
                    v[j] = wlds[m_l*64 + (n_l ^ ((m_l & 7) << 3))];
                }
                *(ushort4*)&CT[((long)bb*ldc + nb + n_l)*N_ + loc + mq*4] = *(ushort4*)v;
            }
        }
    } else {
        float* C = (float*)Cv + zo * Co + zi * Ci;
        #pragma unroll
        for (int fn = 0; fn < 4; ++fn) {
            const int n = nb + fn*16 + rlo;
            const float bv = BIAS ? bias[n] : 0.f;
            #pragma unroll
            for (int fm = 0; fm < 4; ++fm)
                #pragma unroll
                for (int r = 0; r < 4; ++r) {
                    const int m = mb + fm*16 + hi*4 + r;
                    C[(long)m*ldc + n] = acc[fm][fn][r] + bv;
                }
        }
    }
}

// =============== fused xf dual GEMM + gelu + LayerNorm (128x256 tile, full rows) ===============
// xf[m,:] = LN(gelu(U[m,:]·oftT^T + h[m,:]·ww^T + wb)) * lns + lnb   (bf16 out)
// 4 waves side-by-side in N (each 128x64). grid: (128 m-tiles, B_).
__global__ __launch_bounds__(256) void k_xf_ln(
    const unsigned short* __restrict__ Ubf, const unsigned short* __restrict__ oftT,
    const unsigned short* __restrict__ h, const unsigned short* __restrict__ ww,
    const float* __restrict__ wb, const float* __restrict__ lns, const float* __restrict__ lnb,
    unsigned short* __restrict__ xf)
{
    __shared__ unsigned short lds[24576];   // A[0,8192) ushorts, B[8192,24576)
    const int t = threadIdx.x;
    const int wid = t >> 6, lane = t & 63;
    const int m0 = blockIdx.x * 128;
    const int b = blockIdx.y;
    Ubf  += (long)b * N_ * NF_;
    oftT += (long)b * 65536;
    h    += (long)b * N_ * W_;

    const int srow  = t >> 3;
    const int sgran = (t & 7) ^ (srow & 7);
    const int rlo   = lane & 15;
    const int hi    = lane >> 4;

    f32x4 acc[8][4] = {};

    #pragma unroll
    for (int ph = 0; ph < 2; ++ph) {
        const unsigned short* A  = ph ? h  : Ubf;
        const unsigned short* Bp = ph ? ww : oftT;
        for (int k0 = 0; k0 < 256; k0 += 64) {
            __syncthreads();
            #pragma unroll
            for (int j = 0; j < 4; ++j) {
                const unsigned short* ga = A + (long)(m0 + j*32 + srow) * 256 + k0 + sgran*8;
                __builtin_amdgcn_global_load_lds(
                    (const __attribute__((address_space(1))) void*)ga,
                    (__attribute__((address_space(3))) void*)&lds[(j*4 + wid) * 512], 16, 0, 0);
            }
            #pragma unroll
            for (int j = 0; j < 8; ++j) {
                const unsigned short* gb = Bp + (long)(j*32 + srow) * 256 + k0 + sgran*8;
                __builtin_amdgcn_global_load_lds(
                    (const __attribute__((address_space(1))) void*)gb,
                    (__attribute__((address_space(3))) void*)&lds[8192 + (j*4 + wid) * 512], 16, 0, 0);
            }
            __syncthreads();
            #pragma unroll
            for (int kk = 0; kk < 2; ++kk) {
                const int g8 = (((kk*4 + hi) ^ (lane & 7)) << 3);
                bf16x8 bfr[4];
                #pragma unroll
                for (int fn = 0; fn < 4; ++fn)
                    bfr[fn] = *(const bf16x8*)&lds[8192 + (wid*64 + fn*16 + rlo)*64 + g8];
                #pragma unroll
                for (int fm = 0; fm < 8; ++fm) {
                    bf16x8 a = *(const bf16x8*)&lds[(fm*16 + rlo)*64 + g8];
                    #pragma unroll
                    for (int fn = 0; fn < 4; ++fn)
                        acc[fm][fn] = __builtin_amdgcn_mfma_f32_16x16x32_bf16(
                            a, bfr[fn], acc[fm][fn], 0, 0, 0);
                }
            }
        }
    }

    // ---- epilogue: gelu (in-register) + LayerNorm over full 256-wide rows ----
    float wbv[4], lsv[4], lbv[4];
    #pragma unroll
    for (int fn = 0; fn < 4; ++fn) {
        const int c = wid*64 + fn*16 + rlo;
        wbv[fn] = wb[c]; lsv[fn] = lns[c]; lbv[fn] = lnb[c];
    }
    __syncthreads();                       // staging LDS free
    float* sums  = (float*)lds;            // [128][4] wave partial sums
    float* sumsq = (float*)lds + 512;      // [128][4]
    #pragma unroll
    for (int fm = 0; fm < 8; ++fm)
        #pragma unroll
        for (int r = 0; r < 4; ++r) {
            float s = 0.f, s2 = 0.f;
            #pragma unroll
            for (int fn = 0; fn < 4; ++fn) {
                const float g = geluf(acc[fm][fn][r] + wbv[fn]);
                acc[fm][fn][r] = g;
                s += g; s2 += g*g;
            }
            #pragma unroll
            for (int o = 1; o < 16; o <<= 1) { s += __shfl_xor(s, o); s2 += __shfl_xor(s2, o); }
            if (rlo == 0) {
                const int row = fm*16 + hi*4 + r;
                sums [row*4 + wid] = s;
                sumsq[row*4 + wid] = s2;
            }
        }
    __syncthreads();
    #pragma unroll
    for (int fm = 0; fm < 8; ++fm)
        #pragma unroll
        for (int r = 0; r < 4; ++r) {
            const int row = fm*16 + hi*4 + r;
            const float s  = sums [row*4+0] + sums [row*4+1] + sums [row*4+2] + sums [row*4+3];
            const float s2 = sumsq[row*4+0] + sumsq[row*4+1] + sumsq[row*4+2] + sumsq[row*4+3];
            const float mean = s * (1.0f/W_);
            const float var  = s2 * (1.0f/W_) - mean*mean;
            const float inv  = rsqrtf(var + 1e-5f);
            const long mrow = (long)(b*N_ + m0 + row) * W_;
            #pragma unroll
            for (int fn = 0; fn < 4; ++fn) {
                const int c = wid*64 + fn*16 + rlo;
                xf[mrow + c] = f2b((acc[fm][fn][r] - mean)*inv*lsv[fn] + lbv[fn]);
            }
        }
}

// =============== fused: spectral split-K GEMM (blocks [0,256)) + xs GEMM (blocks [256,768)) ======
__global__ __launch_bounds__(256) void k_spec_xs(
    const unsigned short* __restrict__ hT, const unsigned short* __restrict__ UT,
    float* __restrict__ xft_part,
    const unsigned short* __restrict__ h, const unsigned short* __restrict__ linw,
    const float* __restrict__ lin_b, unsigned short* __restrict__ xs)
{
    __shared__ unsigned short lds[16384];
    const int t = threadIdx.x;
    const int wid = t >> 6, lane = t & 63;
    const int wr = wid >> 1, wc = wid & 1;
    const int srow  = t >> 3;
    const int sgran = (t & 7) ^ (srow & 7);
    const int rlo   = lane & 15;
    const int hi    = lane >> 4;
    const int blk = blockIdx.x;

    if (blk < 256) {
        const int bx = blk & 1, by = (blk >> 1) & 1, z = blk >> 2;
        const int zo = z / KS_, zi = z - zo * KS_;
        const unsigned short* A  = hT + (long)zo * W_ * N_ + (long)zi * (N_ / KS_);
        const unsigned short* Bp = UT + (long)zo * NF_ * N_ + (long)zi * (N_ / KS_);
        const int m0 = by * 128, n0 = bx * 128;
        f32x4 acc[4][4] = {};
        for (int k0 = 0; k0 < N_/KS_; k0 += 64) {
            __syncthreads();
            #pragma unroll
            for (int j = 0; j < 4; ++j) {
                const unsigned short* ga = A + (long)(m0 + j*32 + srow) * N_ + k0 + sgran*8;
                __builtin_amdgcn_global_load_lds(
                    (const __attribute__((address_space(1))) void*)ga,
                    (__attribute__((address_space(3))) void*)&lds[(j*4 + wid) * 512], 16, 0, 0);
                const unsigned short* gb = Bp + (long)(n0 + j*32 + srow) * N_ + k0 + sgran*8;
                __builtin_amdgcn_global_load_lds(
                    (const __attribute__((address_space(1))) void*)gb,
                    (__attribute__((address_space(3))) void*)&lds[8192 + (j*4 + wid) * 512], 16, 0, 0);
            }
            __syncthreads();
            #pragma unroll
            for (int kk = 0; kk < 2; ++kk) {
                const int g8 = (((kk*4 + hi) ^ (lane & 7)) << 3);
                bf16x8 a[4], b[4];
                #pragma unroll
                for (int fm = 0; fm < 4; ++fm)
                    a[fm] = *(const bf16x8*)&lds[(wr*64 + fm*16 + rlo)*64 + g8];
                #pragma unroll
                for (int fn = 0; fn < 4; ++fn)
                    b[fn] = *(const bf16x8*)&lds[8192 + (wc*64 + fn*16 + rlo)*64 + g8];
                #pragma unroll
                for (int fm = 0; fm < 4; ++fm)
                    #pragma unroll
                    for (int fn = 0; fn < 4; ++fn)
                        acc[fm][fn] = __builtin_amdgcn_mfma_f32_16x16x32_bf16(
                            a[fm], b[fn], acc[fm][fn], 0, 0, 0);
            }
        }
        float* C = xft_part + (long)zo * KS_ * 65536 + (long)zi * 65536;
        const int mb = m0 + wr*64, nb = n0 + wc*64;
        #pragma unroll
        for (int fn = 0; fn < 4; ++fn) {
            const int n = nb + fn*16 + rlo;
            #pragma unroll
            for (int fm = 0; fm < 4; ++fm)
                #pragma unroll
                for (int r = 0; r < 4; ++r) {
                    const int m = mb + fm*16 + hi*4 + r;
                    C[(long)m*NF_ + n] = acc[fm][fn][r];
                }
        }
    } else {
        const int idx = blk - 256;
        const int bx = idx & 1, by = idx >> 1;
        const int m0 = by * 128, n0 = bx * 128;
        f32x4 acc[4][4] = {};
        for (int k0 = 0; k0 < W_; k0 += 64) {
            __syncthreads();
            #pragma unroll
            for (int j = 0; j < 4; ++j) {
                const unsigned short* ga = h + (long)(m0 + j*32 + srow) * W_ + k0 + sgran*8;
                __builtin_amdgcn_global_load_lds(
                    (const __attribute__((address_space(1))) void*)ga,
                    (__attribute__((address_space(3))) void*)&lds[(j*4 + wid) * 512], 16, 0, 0);
                const unsigned short* gb = linw + (long)(n0 + j*32 + srow) * W_ + k0 + sgran*8;
                __builtin_amdgcn_global_load_lds(
                    (const __attribute__((address_space(1))) void*)gb,
                    (__attribute__((address_space(3))) void*)&lds[8192 + (j*4 + wid) * 512], 16, 0, 0);
            }
            __syncthreads();
            #pragma unroll
            for (int kk = 0; kk < 2; ++kk) {
                const int g8 = (((kk*4 + hi) ^ (lane & 7)) << 3);
                bf16x8 a[4], b[4];
                #pragma unroll
                for (int fm = 0; fm < 4; ++fm)
                    a[fm] = *(const bf16x8*)&lds[(wr*64 + fm*16 + rlo)*64 + g8];
                #pragma unroll
                for (int fn = 0; fn < 4; ++fn)
                    b[fn] = *(const bf16x8*)&lds[8192 + (wc*64 + fn*16 + rlo)*64 + g8];
                #pragma unroll
                for (int fm = 0; fm < 4; ++fm)
                    #pragma unroll
                    for (int fn = 0; fn < 4; ++fn)
                        acc[fm][fn] = __builtin_amdgcn_mfma_f32_16x16x32_bf16(
                            a[fm], b[fn], acc[fm][fn], 0, 0, 0);
            }
        }
        const int mb = m0 + wr*64, nb = n0 + wc*64;
        #pragma unroll
        for (int fn = 0; fn < 4; ++fn) {
            const int n = nb + fn*16 + rlo;
            const float lb = lin_b[n];
            #pragma unroll
            for (int fm = 0; fm < 4; ++fm)
                #pragma unroll
                for (int r = 0; r < 4; ++r) {
                    const int m = mb + fm*16 + hi*4 + r;
                    xs[(long)m*W_ + n] = f2b(acc[fm][fn][r] + lb);
                }
        }
    }
}

// =============== fused: fourier_mul (blocks [0,256)) + gate_agg (blocks [256,256+BN/4)) ======
__global__ __launch_bounds__(256) void k_four_gate(
    const float* __restrict__ fw, const float* __restrict__ xftT,
    unsigned short* __restrict__ oftT,
    const int* __restrict__ offsets, const int* __restrict__ srcp,
    const float* __restrict__ ewt_p, const float* __restrict__ lif,
    const float* __restrict__ eww, const float* __restrict__ ewb,
    const float* __restrict__ g1w, const float* __restrict__ g1b,
    const float* __restrict__ g2w, const float* __restrict__ g2b,
    const unsigned short* __restrict__ xs, unsigned short* __restrict__ xsn)
{
    const int lane = threadIdx.x & 63;
    if (blockIdx.x < 256) {
        const int o = blockIdx.x, f = threadIdx.x;
        const float* fwp = fw + (long)o * NF_ + f;
        float a0 = 0.f, a1 = 0.f;
        #pragma unroll 8
        for (int i = 0; i < W_; ++i) {
            float w = fwp[(long)i * W_ * NF_];
            a0 = fmaf(xftT[i*NF_ + f], w, a0);
            a1 = fmaf(xftT[65536 + i*NF_ + f], w, a1);
        }
        oftT[o*NF_ + f] = f2b(a0);
        oftT[65536 + o*NF_ + f] = f2b(a1);
    } else {
        const int node = (blockIdx.x - 256) * 4 + (threadIdx.x >> 6);
        const int beg = offsets[node], end = offsets[node + 1];
        float lifd[16];
        #pragma unroll
        for (int j = 0; j < 16; ++j) lifd[j] = lif[node*16 + j];
        float a0=0.f, a1=0.f, a2=0.f, a3=0.f;
        for (int c0 = beg; c0 < end; c0 += 64) {
            const int p = c0 + lane;
            float gate = 0.f; int src = 0;
            if (p < end) {
                src = srcp[p];
                const float wv = ewt_p[p];
                float t0 = g1b[0], t1 = g1b[1], t2 = g1b[2];
                #pragma unroll
                for (int j = 0; j < 16; ++j) {
                    const float e0 = fmaf(wv, eww[j], ewb[j]);
                    const float l1 = lifd[j];
                    const float l2 = lif[src*16 + j];
                    t0 = fmaf(g1w[j], e0, t0);
                    t0 = fmaf(g1w[16 + j], l1, t0);
                    t0 = fmaf(g1w[32 + j], l2, t0);
                    t1 = fmaf(g1w[48 + j], e0, t1);
                    t1 = fmaf(g1w[64 + j], l1, t1);
                    t1 = fmaf(g1w[80 + j], l2, t1);
                    t2 = fmaf(g1w[96 + j], e0, t2);
                    t2 = fmaf(g1w[112 + j], l1, t2);
                    t2 = fmaf(g1w[128 + j], l2, t2);
                }
                float z = g2b[0];
                z = fmaf(g2w[0], fmaxf(t0, 0.f), z);
                z = fmaf(g2w[1], fmaxf(t1, 0.f), z);
                z = fmaf(g2w[2], fmaxf(t2, 0.f), z);
                gate = 1.f / (1.f + __expf(-z));
            }
            const int m = min(64, end - c0);
            for (int j = 0; j < m; ++j) {
                const float gv = __shfl(gate, j);
                const int   s  = __shfl(src, j);
                ushort4 v = *(const ushort4*)&xs[(long)s * W_ + lane * 4];
                a0 = fmaf(b2f(v.x), gv, a0);
                a1 = fmaf(b2f(v.y), gv, a1);
                a2 = fmaf(b2f(v.z), gv, a2);
                a3 = fmaf(b2f(v.w), gv, a3);
            }
        }
        float s = a0*a0 + a1*a1 + a2*a2 + a3*a3;
        #pragma unroll
        for (int o = 32; o; o >>= 1) s += __shfl_xor(s, o);
        float inv = 1.f / fmaxf(sqrtf(s), 1e-12f);
        ushort4 r = {f2b(a0*inv), f2b(a1*inv), f2b(a2*inv), f2b(a3*inv)};
        *(ushort4*)(xsn + (long)node * W_ + lane * 4) = r;
    }
}

// =============== fused prologue: weight cvt + U cvt/transpose + in_proj(+hT) ===============
__global__ __launch_bounds__(256) void k_prologue(
    const float* __restrict__ w_w, const float* __restrict__ lin_w,
    const float* __restrict__ proj_w, const float* __restrict__ q1_w,
    unsigned short* __restrict__ wwb, unsigned short* __restrict__ linwb,
    unsigned short* __restrict__ projwb, unsigned short* __restrict__ q1wb,
    const float* __restrict__ U, unsigned short* __restrict__ UT, unsigned short* __restrict__ UL,
    const float* __restrict__ x, const float* __restrict__ pw, const float* __restrict__ pb,
    unsigned short* __restrict__ h, unsigned short* __restrict__ hT)
{
    __shared__ unsigned short tile[64][72];
    const int blk = blockIdx.x;
    const int t = threadIdx.x;
    if (blk < 672) {
        const float* s; unsigned short* d; long base;
        if (blk < 256)      { s = w_w;    d = wwb;    base = (long)blk * 1024; }
        else if (blk < 512) { s = lin_w;  d = linwb;  base = (long)(blk-256) * 1024; }
        else if (blk < 640) { s = proj_w; d = projwb; base = (long)(blk-512) * 1024; }
        else                { s = q1_w;   d = q1wb;   base = (long)(blk-640) * 1024; }
        long i = base + (long)t * 4;
        float4 v = *(const float4*)&s[i];
        ushort4 u = {f2b(v.x), f2b(v.y), f2b(v.z), f2b(v.w)};
        *(ushort4*)&d[i] = u;
    } else if (blk < 2720) {
        const int lb = blk - 672;
        const int b = lb >> 10;
        const int rem = lb & 1023;
        const int cy = rem >> 2, cx = rem & 3;
        const float* src = U + (long)b * N_ * NF_;
        unsigned short* dT = UT + (long)b * N_ * NF_;
        unsigned short* dL = UL + (long)b * N_ * NF_;
        const int r0 = cy * 64, c0 = cx * 64;
        const int lr = t >> 4, lc4 = (t & 15) * 4;
        #pragma unroll
        for (int p = 0; p < 4; ++p) {
            int r = p*16 + lr;
            float4 v = *(const float4*)&src[(long)(r0+r)*NF_ + c0 + lc4];
            ushort4 u = {f2b(v.x), f2b(v.y), f2b(v.z), f2b(v.w)};
            *(ushort4*)&dL[(long)(r0+r)*NF_ + c0 + lc4] = u;
            tile[r][lc4+0]=u.x; tile[r][lc4+1]=u.y; tile[r][lc4+2]=u.z; tile[r][lc4+3]=u.w;
        }
        __syncthreads();
        #pragma unroll
        for (int p = 0; p < 4; ++p) {
            int c = p*16 + lr;
            ushort4 u = {tile[lc4+0][c], tile[lc4+1][c], tile[lc4+2][c], tile[lc4+3][c]};
            *(ushort4*)&dT[(long)(c0+c)*N_ + r0 + lc4] = u;
        }
    } else {
        const int lb = blk - 2720;
        const int b = lb >> 10;
        const int rem = lb & 1023;
        const int ry = rem >> 2, rx = rem & 3;
        const int r0 = ry * 64, c0 = rx * 64;
        const int lr = t >> 4, lc4 = (t & 15) * 4;
        float pwv[12], pbv4[4];
        #pragma unroll
        for (int j = 0; j < 4; ++j) {
            const int w = c0 + lc4 + j;
            pwv[j*3+0] = pw[w*3+0]; pwv[j*3+1] = pw[w*3+1]; pwv[j*3+2] = pw[w*3+2];
            pbv4[j] = pb[w];
        }
        #pragma unroll
        for (int p = 0; p < 4; ++p) {
            const int r = p*16 + lr;
            const float* xr = x + (long)(b*N_ + r0 + r) * 3;
            const float x0 = xr[0], x1 = xr[1], x2 = xr[2];
            ushort4 u;
            u.x = f2b(fmaf(x0,pwv[0],fmaf(x1,pwv[1],fmaf(x2,pwv[2],pbv4[0]))));
            u.y = f2b(fmaf(x0,pwv[3],fmaf(x1,pwv[4],fmaf(x2,pwv[5],pbv4[1]))));
            u.z = f2b(fmaf(x0,pwv[6],fmaf(x1,pwv[7],fmaf(x2,pwv[8],pbv4[2]))));
            u.w = f2b(fmaf(x0,pwv[9],fmaf(x1,pwv[10],fmaf(x2,pwv[11],pbv4[3]))));
            *(ushort4*)&h[(long)(b*N_ + r0 + r)*W_ + c0 + lc4] = u;
            tile[r][lc4+0]=u.x; tile[r][lc4+1]=u.y; tile[r][lc4+2]=u.z; tile[r][lc4+3]=u.w;
        }
        __syncthreads();
        #pragma unroll
        for (int p = 0; p < 4; ++p) {
            const int c = p*16 + lr;
            ushort4 u = {tile[lc4+0][c], tile[lc4+1][c], tile[lc4+2][c], tile[lc4+3][c]};
            *(ushort4*)&hT[((long)b*W_ + c0 + c)*N_ + r0 + lc4] = u;
        }
    }
}

// =============== small kernels ===============
__global__ __launch_bounds__(256) void k_reduce_ks(
    const float* __restrict__ part, float* __restrict__ outp)
{
    int idx = blockIdx.x * 256 + threadIdx.x;
    int b = idx >> 16, rem = idx & 65535;
    const float* p = part + (long)b * KS_ * 65536 + rem;
    float s = 0.f;
    #pragma unroll 16
    for (int k = 0; k < KS_; ++k) s += p[(long)k * 65536];
    outp[idx] = s;
}

// =============== CSR build ===============
__global__ __launch_bounds__(256) void k_hist(const int* __restrict__ ei, int* __restrict__ count) {
    int e = blockIdx.x * 256 + threadIdx.x;
    atomicAdd(&count[ei[E_ + e]], 1);
}
__global__ __launch_bounds__(1024) void k_scan(const int* __restrict__ count, int* __restrict__ offsets) {
    __shared__ int sums[1024];
    const int t = threadIdx.x;
    const int base = t * 32;
    int s = 0;
    #pragma unroll
    for (int i = 0; i < 32; ++i) s += count[base + i];
    sums[t] = s;
    __syncthreads();
    for (int off = 1; off < 1024; off <<= 1) {
        int v = (t >= off) ? sums[t - off] : 0;
        __syncthreads();
        sums[t] += v;
        __syncthreads();
    }
    int run = (t == 0) ? 0 : sums[t - 1];
    #pragma unroll
    for (int i = 0; i < 32; ++i) { offsets[base + i] = run; run += count[base + i]; }
    if (t == 1023) offsets[BN] = run;
}
__global__ __launch_bounds__(256) void k_place(
    const int* __restrict__ ei, const float* __restrict__ ewt,
    const int* __restrict__ offsets, int* __restrict__ cursor,
    int* __restrict__ srcp, float* __restrict__ ewt_p)
{
    int e = blockIdx.x * 256 + threadIdx.x;
    int dst = ei[E_ + e];
    int pos = offsets[dst] + atomicAdd(&cursor[dst], 1);
    srcp[pos] = ei[e];
    ewt_p[pos] = ewt[e];
}

extern "C" void kernel_launch(void* const* d_in, const int* in_sizes, int n_in,
                              void* d_out, int out_size, void* d_ws, size_t ws_size,
                              hipStream_t stream)
{
    const float* x      = (const float*)d_in[0];
    const float* U      = (const float*)d_in[1];
    const int*   ei     = (const int*)  d_in[2];
    const float* ewt    = (const float*)d_in[3];
    const float* lif    = (const float*)d_in[4];
    const float* p_w    = (const float*)d_in[5];
    const float* p_b    = (const float*)d_in[6];
    const float* four_w = (const float*)d_in[7];
    const float* w_w    = (const float*)d_in[8];
    const float* w_b    = (const float*)d_in[9];
    const float* ln_s   = (const float*)d_in[10];
    const float* ln_b   = (const float*)d_in[11];
    const float* lin_w  = (const float*)d_in[12];
    const float* lin_b  = (const float*)d_in[13];
    const float* ew_w   = (const float*)d_in[14];
    const float* ew_b   = (const float*)d_in[15];
    const float* g1_w   = (const float*)d_in[16];
    const float* g1_b   = (const float*)d_in[17];
    const float* g2_w   = (const float*)d_in[18];
    const float* g2_b   = (const float*)d_in[19];
    const float* proj_w = (const float*)d_in[20];
    const float* proj_b = (const float*)d_in[21];
    const float* q1_w   = (const float*)d_in[22];
    const float* q1_b   = (const float*)d_in[23];
    const float* q2_w   = (const float*)d_in[24];
    const float* q2_b   = (const float*)d_in[25];

    char* wsb = (char*)d_ws;
    size_t off = 0;
    auto alloc = [&](size_t bytes) -> void* {
        void* p = wsb + off; off += (bytes + 255) & ~(size_t)255; return p;
    };
    float* xft_part  = (float*)alloc((size_t)B_ * KS_ * 65536 * 4);
    float* xftT      = (float*)alloc((size_t)B_ * 65536 * 4);
    unsigned short* h_bf   = (unsigned short*)alloc((size_t)BN * W_ * 2);
    unsigned short* hT_bf  = (unsigned short*)alloc((size_t)BN * W_ * 2);
    unsigned short* U_bf   = (unsigned short*)alloc((size_t)BN * NF_ * 2);
    unsigned short* UT_bf  = (unsigned short*)alloc((size_t)BN * NF_ * 2);
    unsigned short* xf_bf  = (unsigned short*)alloc((size_t)BN * W_ * 2);
    unsigned short* xs_bf  = (unsigned short*)alloc((size_t)BN * W_ * 2);
    unsigned short* xsn_bf = (unsigned short*)alloc((size_t)BN * W_ * 2);
    unsigned short* oftT_bf= (unsigned short*)alloc((size_t)B_ * 65536 * 2);
    unsigned short* wwb    = (unsigned short*)alloc((size_t)L_ * W_ * W_ * 2);
    unsigned short* linwb  = (unsigned short*)alloc((size_t)L_ * W_ * W_ * 2);
    unsigned short* projwb = (unsigned short*)alloc((size_t)W_ * 2 * W_ * 2);
    unsigned short* q1wb   = (unsigned short*)alloc((size_t)128 * W_ * 2);
    int*   srcp    = (int*)alloc((size_t)E_ * 4);
    float* ewt_p   = (float*)alloc((size_t)E_ * 4);
    int*   count   = (int*)alloc((size_t)BN * 4);
    int*   cursor  = (int*)alloc((size_t)BN * 4);
    int*   offsets = (int*)alloc((size_t)(BN + 1) * 4);

    // ---- CSR build ----
    hipMemsetAsync(count, 0, (size_t)2 * BN * 4, stream);
    k_hist<<<E_/256, 256, 0, stream>>>(ei, count);
    k_scan<<<1, 1024, 0, stream>>>(count, offsets);
    k_place<<<E_/256, 256, 0, stream>>>(ei, ewt, offsets, cursor, srcp, ewt_p);

    // ---- fused prologue ----
    k_prologue<<<4768, 256, 0, stream>>>(
        w_w, lin_w, proj_w, q1_w, wwb, linwb, projwb, q1wb,
        U, UT_bf, U_bf,
        x, p_w, p_b, h_bf, hT_bf);

    for (int l = 0; l < L_; ++l) {
        // spectral split-K (needs hT) || xs GEMM (needs h only)
        k_spec_xs<<<768, 256, 0, stream>>>(
            hT_bf, UT_bf, xft_part,
            h_bf, linwb + (long)l*W_*W_, lin_b + l*W_, xs_bf);
        k_reduce_ks<<<(B_*65536)/256, 256, 0, stream>>>(xft_part, xftT);
        // fourier (HBM weight stream) || gate_agg (cache gather; long pole)
        k_four_gate<<<256 + BN/4, 256, 0, stream>>>(
            four_w + (long)l*W_*W_*NF_, xftT, oftT_bf,
            offsets, srcp, ewt_p, lif,
            ew_w + l*16, ew_b + l*16, g1_w + l*144, g1_b + l*3,
            g2_w + l*3, g2_b + l, xs_bf, xsn_bf);
        // xf = LN(gelu(U·oftT^T + h·ww^T + wb)) — fused 128x256-tile GEMM epilogue
        k_xf_ln<<<dim3(N_/128, B_), 256, 0, stream>>>(
            U_bf, oftT_bf, h_bf, wwb + (long)l*W_*W_,
            w_b + l*W_, ln_s + l*W_, ln_b + l*W_, xf_bf);
        // h = xf_bf @ projW1^T + xsn @ projW2^T + proj_b; l<3 also emits hT via TROUT
        if (l < 3) {
            k_mfma_nt<true,1,true,false,true><<<dim3(2, BN/128, 1), 256, 0, stream>>>(
                xf_bf, W_, 0, 0,
                projwb, 2*W_, 0, 0, W_,
                xsn_bf, W_, 0,
                projwb + W_, 2*W_, 0, W_,
                h_bf, W_, 0, 0,
                hT_bf, proj_b, nullptr, nullptr, nullptr, 1);
        } else {
            k_mfma_nt<true,1,true><<<dim3(2, BN/128, 1), 256, 0, stream>>>(
                xf_bf, W_, 0, 0,
                projwb, 2*W_, 0, 0, W_,
                xsn_bf, W_, 0,
                projwb + W_, 2*W_, 0, W_,
                h_bf, W_, 0, 0,
                nullptr, proj_b, nullptr, nullptr, nullptr, 1);
        }
    }
    // fused q-head
    k_mfma_nt<false,0,true,true><<<dim3(1, BN/128, 1), 256, 0, stream>>>(
        h_bf, W_, 0, 0,
        q1wb, W_, 0, 0, W_,
        nullptr, 0, 0, nullptr, 0, 0, 0,
        nullptr, 128, 0, 0,
        nullptr, q1_b, q2_w, q2_b, (float*)d_out, 1);
}

// Round 16
// 697.682 us; speedup vs baseline: 1.4747x; 1.4747x over previous
//
#include <hip/hip_runtime.h>
#include <hip/hip_bf16.h>

#define B_ 2
#define N_ 16384
#define BN 32768
#define W_ 256
#define NF_ 256
#define E_ 524288
#define L_ 4
#define KS_ 32   // split-K for spectral fwd

typedef __attribute__((ext_vector_type(8))) short bf16x8;
typedef __attribute__((ext_vector_type(4))) float f32x4;

__device__ __forceinline__ unsigned short f2b(float x) {
    __hip_bfloat16 h = __float2bfloat16(x);
    return *reinterpret_cast<unsigned short*>(&h);
}
__device__ __forceinline__ float b2f(unsigned short u) {
    union { unsigned int i; float f; } c; c.i = ((unsigned int)u) << 16; return c.f;
}
__device__ __forceinline__ float geluf(float x) {
    return 0.5f * x * (1.0f + erff(x * 0.70710678118654752440f));
}

// =============== bf16 MFMA NT GEMM (xf-dual / proj / q-head) ===============
// 128x128 tile, 4 waves of 64x64, BK=64, global_load_lds staging with XOR-swizzled LDS.
// OUTM: 0=f32 store, 1=bf16 store. QHEAD: fused relu-dot epilogue. TROUT: also emit C^T via LDS.
template<bool DUAL, int OUTM, bool BIAS, bool QHEAD = false, bool TROUT = false>
__global__ __launch_bounds__(256) void k_mfma_nt(
    const unsigned short* __restrict__ A1, int lda1, long A1o, long A1i,
    const unsigned short* __restrict__ B1, int ldb1, long B1o, long B1i, int K1,
    const unsigned short* __restrict__ A2, int lda2, long A2o,
    const unsigned short* __restrict__ B2, int ldb2, long B2o, int K2,
    void* __restrict__ Cv, int ldc, long Co, long Ci,
    unsigned short* __restrict__ CT,
    const float* __restrict__ bias,
    const float* __restrict__ qw, const float* __restrict__ q2b,
    float* __restrict__ qout, int zdiv)
{
    __shared__ unsigned short lds[16384];
    const int t = threadIdx.x;
    const int wid = t >> 6, lane = t & 63;
    const int wr = wid >> 1, wc = wid & 1;
    const int m0 = blockIdx.y * 128, n0 = blockIdx.x * 128;
    const int z = blockIdx.z;
    const int zo = z / zdiv, zi = z - zo * zdiv;
    A1 += zo * A1o + zi * A1i;
    B1 += zo * B1o + zi * B1i;
    if (DUAL) { A2 += zo * A2o; B2 += zo * B2o; }

    const int srow  = t >> 3;
    const int sgran = (t & 7) ^ (srow & 7);
    const int rlo   = lane & 15;
    const int hi    = lane >> 4;

    f32x4 acc[4][4] = {};

    const int nph = DUAL ? 2 : 1;
    for (int ph = 0; ph < nph; ++ph) {
        const unsigned short* A  = (DUAL && ph) ? A2 : A1;
        const unsigned short* Bp = (DUAL && ph) ? B2 : B1;
        const int lda = (DUAL && ph) ? lda2 : lda1;
        const int ldb = (DUAL && ph) ? ldb2 : ldb1;
        const int K   = (DUAL && ph) ? K2 : K1;
        for (int k0 = 0; k0 < K; k0 += 64) {
            __syncthreads();
            #pragma unroll
            for (int j = 0; j < 4; ++j) {
                const unsigned short* ga = A + (long)(m0 + j*32 + srow) * lda + k0 + sgran*8;
                __builtin_amdgcn_global_load_lds(
                    (const __attribute__((address_space(1))) void*)ga,
                    (__attribute__((address_space(3))) void*)&lds[(j*4 + wid) * 512],
                    16, 0, 0);
            }
            #pragma unroll
            for (int j = 0; j < 4; ++j) {
                const unsigned short* gb = Bp + (long)(n0 + j*32 + srow) * ldb + k0 + sgran*8;
                __builtin_amdgcn_global_load_lds(
                    (const __attribute__((address_space(1))) void*)gb,
                    (__attribute__((address_space(3))) void*)&lds[8192 + (j*4 + wid) * 512],
                    16, 0, 0);
            }
            __syncthreads();
            #pragma unroll
            for (int kk = 0; kk < 2; ++kk) {
                const int g8 = (((kk*4 + hi) ^ (lane & 7)) << 3);
                bf16x8 a[4], b[4];
                #pragma unroll
                for (int fm = 0; fm < 4; ++fm)
                    a[fm] = *(const bf16x8*)&lds[(wr*64 + fm*16 + rlo)*64 + g8];
                #pragma unroll
                for (int fn = 0; fn < 4; ++fn)
                    b[fn] = *(const bf16x8*)&lds[8192 + (wc*64 + fn*16 + rlo)*64 + g8];
                #pragma unroll
                for (int fm = 0; fm < 4; ++fm)
                    #pragma unroll
                    for (int fn = 0; fn < 4; ++fn)
                        acc[fm][fn] = __builtin_amdgcn_mfma_f32_16x16x32_bf16(
                            a[fm], b[fn], acc[fm][fn], 0, 0, 0);
            }
        }
    }

    const int mb = m0 + wr*64, nb = n0 + wc*64;
    if (QHEAD) {
        __syncthreads();
        float* rs = (float*)lds;
        if (t < 128) rs[t] = 0.f;
        __syncthreads();
        #pragma unroll
        for (int fm = 0; fm < 4; ++fm)
            #pragma unroll
            for (int r = 0; r < 4; ++r) {
                const int m_l = wr*64 + fm*16 + hi*4 + r;
                float part = 0.f;
                #pragma unroll
                for (int fn = 0; fn < 4; ++fn) {
                    const int n = nb + fn*16 + rlo;
                    part += fmaxf(acc[fm][fn][r] + bias[n], 0.f) * qw[n];
                }
                #pragma unroll
                for (int o = 8; o; o >>= 1) part += __shfl_xor(part, o);
                if (rlo == 0) atomicAdd(&rs[m_l], part);
            }
        __syncthreads();
        if (t < 128) qout[m0 + t] = rs[t] + q2b[0];
    } else if (OUTM == 1) {
        unsigned short* C = (unsigned short*)Cv + zo * Co + zi * Ci;
        #pragma unroll
        for (int fn = 0; fn < 4; ++fn) {
            const int n = nb + fn*16 + rlo;
            const float bv = BIAS ? bias[n] : 0.f;
            #pragma unroll
            for (int fm = 0; fm < 4; ++fm)
                #pragma unroll
                for (int r = 0; r < 4; ++r) {
                    const int m = mb + fm*16 + hi*4 + r;
                    C[(long)m*ldc + n] = f2b(acc[fm][fn][r] + bv);
                }
        }
        if (TROUT) {
            __syncthreads();
            unsigned short* wlds = &lds[wid * 4096];
            #pragma unroll
            for (int fm = 0; fm < 4; ++fm)
                #pragma unroll
                for (int r = 0; r < 4; ++r) {
                    const int m_l = fm*16 + hi*4 + r;
                    const int sw = (m_l & 7) << 3;
                    #pragma unroll
                    for (int fn = 0; fn < 4; ++fn) {
                        const int n_l = fn*16 + rlo;
                        const float bv = BIAS ? bias[nb + n_l] : 0.f;
                        wlds[m_l*64 + (n_l ^ sw)] = f2b(acc[fm][fn][r] + bv);
                    }
                }
            const int bb = mb >> 14, loc = mb & 16383;
            const int mq = lane & 15, nq = lane >> 4;
            #pragma unroll
            for (int p = 0; p < 16; ++p) {
                const int n_l = p*4 + nq;
                unsigned short v[4];
                #pragma unroll
                for (int j = 0; j < 4; ++j) {
                    const int m_l = mq*4 + j;
                    v[j] = wlds[m_l*64 + (n_l ^ ((m_l & 7) << 3))];
                }
                *(ushort4*)&CT[((long)bb*ldc + nb + n_l)*N_ + loc + mq*4] = *(ushort4*)v;
            }
        }
    } else {
        float* C = (float*)Cv + zo * Co + zi * Ci;
        #pragma unroll
        for (int fn = 0; fn < 4; ++fn) {
            const int n = nb + fn*16 + rlo;
            const float bv = BIAS ? bias[n] : 0.f;
            #pragma unroll
            for (int fm = 0; fm < 4; ++fm)
                #pragma unroll
                for (int r = 0; r < 4; ++r) {
                    const int m = mb + fm*16 + hi*4 + r;
                    C[(long)m*ldc + n] = acc[fm][fn][r] + bv;
                }
        }
    }
}

// =============== fused: spectral split-K GEMM (blocks [0,256)) + xs GEMM (blocks [256,768)) ======
// spectral: part[zo*KS+zi][w][f] = sum over n-chunk of hT[zo][w][n]·UT[zo][f][n]   (f32)
// xs:       xs[m][n] = sum_k h[m][k]·lin[n][k] + lin_b[n]                          (bf16)
__global__ __launch_bounds__(256) void k_spec_xs(
    const unsigned short* __restrict__ hT, const unsigned short* __restrict__ UT,
    float* __restrict__ xft_part,
    const unsigned short* __restrict__ h, const unsigned short* __restrict__ linw,
    const float* __restrict__ lin_b, unsigned short* __restrict__ xs)
{
    __shared__ unsigned short lds[16384];
    const int t = threadIdx.x;
    const int wid = t >> 6, lane = t & 63;
    const int wr = wid >> 1, wc = wid & 1;
    const int srow  = t >> 3;
    const int sgran = (t & 7) ^ (srow & 7);
    const int rlo   = lane & 15;
    const int hi    = lane >> 4;
    const int blk = blockIdx.x;

    if (blk < 256) {
        const int bx = blk & 1, by = (blk >> 1) & 1, z = blk >> 2;
        const int zo = z / KS_, zi = z - zo * KS_;
        const unsigned short* A  = hT + (long)zo * W_ * N_ + (long)zi * (N_ / KS_);
        const unsigned short* Bp = UT + (long)zo * NF_ * N_ + (long)zi * (N_ / KS_);
        const int m0 = by * 128, n0 = bx * 128;
        f32x4 acc[4][4] = {};
        for (int k0 = 0; k0 < N_/KS_; k0 += 64) {
            __syncthreads();
            #pragma unroll
            for (int j = 0; j < 4; ++j) {
                const unsigned short* ga = A + (long)(m0 + j*32 + srow) * N_ + k0 + sgran*8;
                __builtin_amdgcn_global_load_lds(
                    (const __attribute__((address_space(1))) void*)ga,
                    (__attribute__((address_space(3))) void*)&lds[(j*4 + wid) * 512], 16, 0, 0);
                const unsigned short* gb = Bp + (long)(n0 + j*32 + srow) * N_ + k0 + sgran*8;
                __builtin_amdgcn_global_load_lds(
                    (const __attribute__((address_space(1))) void*)gb,
                    (__attribute__((address_space(3))) void*)&lds[8192 + (j*4 + wid) * 512], 16, 0, 0);
            }
            __syncthreads();
            #pragma unroll
            for (int kk = 0; kk < 2; ++kk) {
                const int g8 = (((kk*4 + hi) ^ (lane & 7)) << 3);
                bf16x8 a[4], b[4];
                #pragma unroll
                for (int fm = 0; fm < 4; ++fm)
                    a[fm] = *(const bf16x8*)&lds[(wr*64 + fm*16 + rlo)*64 + g8];
                #pragma unroll
                for (int fn = 0; fn < 4; ++fn)
                    b[fn] = *(const bf16x8*)&lds[8192 + (wc*64 + fn*16 + rlo)*64 + g8];
                #pragma unroll
                for (int fm = 0; fm < 4; ++fm)
                    #pragma unroll
                    for (int fn = 0; fn < 4; ++fn)
                        acc[fm][fn] = __builtin_amdgcn_mfma_f32_16x16x32_bf16(
                            a[fm], b[fn], acc[fm][fn], 0, 0, 0);
            }
        }
        float* C = xft_part + (long)zo * KS_ * 65536 + (long)zi * 65536;
        const int mb = m0 + wr*64, nb = n0 + wc*64;
        #pragma unroll
        for (int fn = 0; fn < 4; ++fn) {
            const int n = nb + fn*16 + rlo;
            #pragma unroll
            for (int fm = 0; fm < 4; ++fm)
                #pragma unroll
                for (int r = 0; r < 4; ++r) {
                    const int m = mb + fm*16 + hi*4 + r;
                    C[(long)m*NF_ + n] = acc[fm][fn][r];
                }
        }
    } else {
        const int idx = blk - 256;
        const int bx = idx & 1, by = idx >> 1;
        const int m0 = by * 128, n0 = bx * 128;
        f32x4 acc[4][4] = {};
        for (int k0 = 0; k0 < W_; k0 += 64) {
            __syncthreads();
            #pragma unroll
            for (int j = 0; j < 4; ++j) {
                const unsigned short* ga = h + (long)(m0 + j*32 + srow) * W_ + k0 + sgran*8;
                __builtin_amdgcn_global_load_lds(
                    (const __attribute__((address_space(1))) void*)ga,
                    (__attribute__((address_space(3))) void*)&lds[(j*4 + wid) * 512], 16, 0, 0);
                const unsigned short* gb = linw + (long)(n0 + j*32 + srow) * W_ + k0 + sgran*8;
                __builtin_amdgcn_global_load_lds(
                    (const __attribute__((address_space(1))) void*)gb,
                    (__attribute__((address_space(3))) void*)&lds[8192 + (j*4 + wid) * 512], 16, 0, 0);
            }
            __syncthreads();
            #pragma unroll
            for (int kk = 0; kk < 2; ++kk) {
                const int g8 = (((kk*4 + hi) ^ (lane & 7)) << 3);
                bf16x8 a[4], b[4];
                #pragma unroll
                for (int fm = 0; fm < 4; ++fm)
                    a[fm] = *(const bf16x8*)&lds[(wr*64 + fm*16 + rlo)*64 + g8];
                #pragma unroll
                for (int fn = 0; fn < 4; ++fn)
                    b[fn] = *(const bf16x8*)&lds[8192 + (wc*64 + fn*16 + rlo)*64 + g8];
                #pragma unroll
                for (int fm = 0; fm < 4; ++fm)
                    #pragma unroll
                    for (int fn = 0; fn < 4; ++fn)
                        acc[fm][fn] = __builtin_amdgcn_mfma_f32_16x16x32_bf16(
                            a[fm], b[fn], acc[fm][fn], 0, 0, 0);
            }
        }
        const int mb = m0 + wr*64, nb = n0 + wc*64;
        #pragma unroll
        for (int fn = 0; fn < 4; ++fn) {
            const int n = nb + fn*16 + rlo;
            const float lb = lin_b[n];
            #pragma unroll
            for (int fm = 0; fm < 4; ++fm)
                #pragma unroll
                for (int r = 0; r < 4; ++r) {
                    const int m = mb + fm*16 + hi*4 + r;
                    xs[(long)m*W_ + n] = f2b(acc[fm][fn][r] + lb);
                }
        }
    }
}

// =============== fused: fourier_mul (blocks [0,256)) + gate_agg (blocks [256,256+BN/4)) ======
__global__ __launch_bounds__(256) void k_four_gate(
    const float* __restrict__ fw, const float* __restrict__ xftT,
    unsigned short* __restrict__ oftT,
    const int* __restrict__ offsets, const int* __restrict__ srcp,
    const float* __restrict__ ewt_p, const float* __restrict__ lif,
    const float* __restrict__ eww, const float* __restrict__ ewb,
    const float* __restrict__ g1w, const float* __restrict__ g1b,
    const float* __restrict__ g2w, const float* __restrict__ g2b,
    const unsigned short* __restrict__ xs, unsigned short* __restrict__ xsn)
{
    const int lane = threadIdx.x & 63;
    if (blockIdx.x < 256) {
        const int o = blockIdx.x, f = threadIdx.x;
        const float* fwp = fw + (long)o * NF_ + f;
        float a0 = 0.f, a1 = 0.f;
        #pragma unroll 8
        for (int i = 0; i < W_; ++i) {
            float w = fwp[(long)i * W_ * NF_];
            a0 = fmaf(xftT[i*NF_ + f], w, a0);
            a1 = fmaf(xftT[65536 + i*NF_ + f], w, a1);
        }
        oftT[o*NF_ + f] = f2b(a0);
        oftT[65536 + o*NF_ + f] = f2b(a1);
    } else {
        const int node = (blockIdx.x - 256) * 4 + (threadIdx.x >> 6);
        const int beg = offsets[node], end = offsets[node + 1];
        float lifd[16];
        #pragma unroll
        for (int j = 0; j < 16; ++j) lifd[j] = lif[node*16 + j];
        float a0=0.f, a1=0.f, a2=0.f, a3=0.f;
        for (int c0 = beg; c0 < end; c0 += 64) {
            const int p = c0 + lane;
            float gate = 0.f; int src = 0;
            if (p < end) {
                src = srcp[p];
                const float wv = ewt_p[p];
                float t0 = g1b[0], t1 = g1b[1], t2 = g1b[2];
                #pragma unroll
                for (int j = 0; j < 16; ++j) {
                    const float e0 = fmaf(wv, eww[j], ewb[j]);
                    const float l1 = lifd[j];
                    const float l2 = lif[src*16 + j];
                    t0 = fmaf(g1w[j], e0, t0);
                    t0 = fmaf(g1w[16 + j], l1, t0);
                    t0 = fmaf(g1w[32 + j], l2, t0);
                    t1 = fmaf(g1w[48 + j], e0, t1);
                    t1 = fmaf(g1w[64 + j], l1, t1);
                    t1 = fmaf(g1w[80 + j], l2, t1);
                    t2 = fmaf(g1w[96 + j], e0, t2);
                    t2 = fmaf(g1w[112 + j], l1, t2);
                    t2 = fmaf(g1w[128 + j], l2, t2);
                }
                float z = g2b[0];
                z = fmaf(g2w[0], fmaxf(t0, 0.f), z);
                z = fmaf(g2w[1], fmaxf(t1, 0.f), z);
                z = fmaf(g2w[2], fmaxf(t2, 0.f), z);
                gate = 1.f / (1.f + __expf(-z));
            }
            const int m = min(64, end - c0);
            for (int j = 0; j < m; ++j) {
                const float gv = __shfl(gate, j);
                const int   s  = __shfl(src, j);
                ushort4 v = *(const ushort4*)&xs[(long)s * W_ + lane * 4];
                a0 = fmaf(b2f(v.x), gv, a0);
                a1 = fmaf(b2f(v.y), gv, a1);
                a2 = fmaf(b2f(v.z), gv, a2);
                a3 = fmaf(b2f(v.w), gv, a3);
            }
        }
        float s = a0*a0 + a1*a1 + a2*a2 + a3*a3;
        #pragma unroll
        for (int o = 32; o; o >>= 1) s += __shfl_xor(s, o);
        float inv = 1.f / fmaxf(sqrtf(s), 1e-12f);
        ushort4 r = {f2b(a0*inv), f2b(a1*inv), f2b(a2*inv), f2b(a3*inv)};
        *(ushort4*)(xsn + (long)node * W_ + lane * 4) = r;
    }
}

// =============== fused prologue: weight cvt + U cvt/transpose + in_proj(+hT) ===============
__global__ __launch_bounds__(256) void k_prologue(
    const float* __restrict__ w_w, const float* __restrict__ lin_w,
    const float* __restrict__ proj_w, const float* __restrict__ q1_w,
    unsigned short* __restrict__ wwb, unsigned short* __restrict__ linwb,
    unsigned short* __restrict__ projwb, unsigned short* __restrict__ q1wb,
    const float* __restrict__ U, unsigned short* __restrict__ UT, unsigned short* __restrict__ UL,
    const float* __restrict__ x, const float* __restrict__ pw, const float* __restrict__ pb,
    unsigned short* __restrict__ h, unsigned short* __restrict__ hT)
{
    __shared__ unsigned short tile[64][72];
    const int blk = blockIdx.x;
    const int t = threadIdx.x;
    if (blk < 672) {
        const float* s; unsigned short* d; long base;
        if (blk < 256)      { s = w_w;    d = wwb;    base = (long)blk * 1024; }
        else if (blk < 512) { s = lin_w;  d = linwb;  base = (long)(blk-256) * 1024; }
        else if (blk < 640) { s = proj_w; d = projwb; base = (long)(blk-512) * 1024; }
        else                { s = q1_w;   d = q1wb;   base = (long)(blk-640) * 1024; }
        long i = base + (long)t * 4;
        float4 v = *(const float4*)&s[i];
        ushort4 u = {f2b(v.x), f2b(v.y), f2b(v.z), f2b(v.w)};
        *(ushort4*)&d[i] = u;
    } else if (blk < 2720) {
        const int lb = blk - 672;
        const int b = lb >> 10;
        const int rem = lb & 1023;
        const int cy = rem >> 2, cx = rem & 3;
        const float* src = U + (long)b * N_ * NF_;
        unsigned short* dT = UT + (long)b * N_ * NF_;
        unsigned short* dL = UL + (long)b * N_ * NF_;
        const int r0 = cy * 64, c0 = cx * 64;
        const int lr = t >> 4, lc4 = (t & 15) * 4;
        #pragma unroll
        for (int p = 0; p < 4; ++p) {
            int r = p*16 + lr;
            float4 v = *(const float4*)&src[(long)(r0+r)*NF_ + c0 + lc4];
            ushort4 u = {f2b(v.x), f2b(v.y), f2b(v.z), f2b(v.w)};
            *(ushort4*)&dL[(long)(r0+r)*NF_ + c0 + lc4] = u;
            tile[r][lc4+0]=u.x; tile[r][lc4+1]=u.y; tile[r][lc4+2]=u.z; tile[r][lc4+3]=u.w;
        }
        __syncthreads();
        #pragma unroll
        for (int p = 0; p < 4; ++p) {
            int c = p*16 + lr;
            ushort4 u = {tile[lc4+0][c], tile[lc4+1][c], tile[lc4+2][c], tile[lc4+3][c]};
            *(ushort4*)&dT[(long)(c0+c)*N_ + r0 + lc4] = u;
        }
    } else {
        const int lb = blk - 2720;
        const int b = lb >> 10;
        const int rem = lb & 1023;
        const int ry = rem >> 2, rx = rem & 3;
        const int r0 = ry * 64, c0 = rx * 64;
        const int lr = t >> 4, lc4 = (t & 15) * 4;
        float pwv[12], pbv4[4];
        #pragma unroll
        for (int j = 0; j < 4; ++j) {
            const int w = c0 + lc4 + j;
            pwv[j*3+0] = pw[w*3+0]; pwv[j*3+1] = pw[w*3+1]; pwv[j*3+2] = pw[w*3+2];
            pbv4[j] = pb[w];
        }
        #pragma unroll
        for (int p = 0; p < 4; ++p) {
            const int r = p*16 + lr;
            const float* xr = x + (long)(b*N_ + r0 + r) * 3;
            const float x0 = xr[0], x1 = xr[1], x2 = xr[2];
            ushort4 u;
            u.x = f2b(fmaf(x0,pwv[0],fmaf(x1,pwv[1],fmaf(x2,pwv[2],pbv4[0]))));
            u.y = f2b(fmaf(x0,pwv[3],fmaf(x1,pwv[4],fmaf(x2,pwv[5],pbv4[1]))));
            u.z = f2b(fmaf(x0,pwv[6],fmaf(x1,pwv[7],fmaf(x2,pwv[8],pbv4[2]))));
            u.w = f2b(fmaf(x0,pwv[9],fmaf(x1,pwv[10],fmaf(x2,pwv[11],pbv4[3]))));
            *(ushort4*)&h[(long)(b*N_ + r0 + r)*W_ + c0 + lc4] = u;
            tile[r][lc4+0]=u.x; tile[r][lc4+1]=u.y; tile[r][lc4+2]=u.z; tile[r][lc4+3]=u.w;
        }
        __syncthreads();
        #pragma unroll
        for (int p = 0; p < 4; ++p) {
            const int c = p*16 + lr;
            ushort4 u = {tile[lc4+0][c], tile[lc4+1][c], tile[lc4+2][c], tile[lc4+3][c]};
            *(ushort4*)&hT[((long)b*W_ + c0 + c)*N_ + r0 + lc4] = u;
        }
    }
}

// =============== small kernels ===============
__global__ __launch_bounds__(256) void k_reduce_ks(
    const float* __restrict__ part, float* __restrict__ outp)
{
    int idx = blockIdx.x * 256 + threadIdx.x;
    int b = idx >> 16, rem = idx & 65535;
    const float* p = part + (long)b * KS_ * 65536 + rem;
    float s = 0.f;
    #pragma unroll 16
    for (int k = 0; k < KS_; ++k) s += p[(long)k * 65536];
    outp[idx] = s;
}

__global__ __launch_bounds__(256) void k_gelu_ln(
    const unsigned short* __restrict__ xf, unsigned short* __restrict__ out,
    const float* __restrict__ wb, const float* __restrict__ lns, const float* __restrict__ lnb)
{
    const int node = blockIdx.x * 4 + (threadIdx.x >> 6);
    const int lane = threadIdx.x & 63;
    ushort4 v4 = *(const ushort4*)(xf + (long)node*W_ + lane*4);
    float4 bb = *(const float4*)(wb + lane*4);
    float e0 = geluf(b2f(v4.x)+bb.x), e1 = geluf(b2f(v4.y)+bb.y);
    float e2 = geluf(b2f(v4.z)+bb.z), e3 = geluf(b2f(v4.w)+bb.w);
    float s  = e0+e1+e2+e3;
    float s2 = e0*e0+e1*e1+e2*e2+e3*e3;
    #pragma unroll
    for (int o = 32; o; o >>= 1) { s += __shfl_xor(s, o); s2 += __shfl_xor(s2, o); }
    float mean = s * (1.0f/W_);
    float var  = s2 * (1.0f/W_) - mean*mean;
    float inv = rsqrtf(var + 1e-5f);
    float4 sc = *(const float4*)(lns + lane*4);
    float4 bi = *(const float4*)(lnb + lane*4);
    ushort4 o4;
    o4.x = f2b((e0-mean)*inv*sc.x + bi.x);
    o4.y = f2b((e1-mean)*inv*sc.y + bi.y);
    o4.z = f2b((e2-mean)*inv*sc.z + bi.z);
    o4.w = f2b((e3-mean)*inv*sc.w + bi.w);
    *(ushort4*)(out + (long)node*W_ + lane*4) = o4;
}

// =============== CSR build ===============
__global__ __launch_bounds__(256) void k_hist(const int* __restrict__ ei, int* __restrict__ count) {
    int e = blockIdx.x * 256 + threadIdx.x;
    atomicAdd(&count[ei[E_ + e]], 1);
}
__global__ __launch_bounds__(1024) void k_scan(const int* __restrict__ count, int* __restrict__ offsets) {
    __shared__ int sums[1024];
    const int t = threadIdx.x;
    const int base = t * 32;
    int s = 0;
    #pragma unroll
    for (int i = 0; i < 32; ++i) s += count[base + i];
    sums[t] = s;
    __syncthreads();
    for (int off = 1; off < 1024; off <<= 1) {
        int v = (t >= off) ? sums[t - off] : 0;
        __syncthreads();
        sums[t] += v;
        __syncthreads();
    }
    int run = (t == 0) ? 0 : sums[t - 1];
    #pragma unroll
    for (int i = 0; i < 32; ++i) { offsets[base + i] = run; run += count[base + i]; }
    if (t == 1023) offsets[BN] = run;
}
__global__ __launch_bounds__(256) void k_place(
    const int* __restrict__ ei, const float* __restrict__ ewt,
    const int* __restrict__ offsets, int* __restrict__ cursor,
    int* __restrict__ srcp, float* __restrict__ ewt_p)
{
    int e = blockIdx.x * 256 + threadIdx.x;
    int dst = ei[E_ + e];
    int pos = offsets[dst] + atomicAdd(&cursor[dst], 1);
    srcp[pos] = ei[e];
    ewt_p[pos] = ewt[e];
}

extern "C" void kernel_launch(void* const* d_in, const int* in_sizes, int n_in,
                              void* d_out, int out_size, void* d_ws, size_t ws_size,
                              hipStream_t stream)
{
    const float* x      = (const float*)d_in[0];
    const float* U      = (const float*)d_in[1];
    const int*   ei     = (const int*)  d_in[2];
    const float* ewt    = (const float*)d_in[3];
    const float* lif    = (const float*)d_in[4];
    const float* p_w    = (const float*)d_in[5];
    const float* p_b    = (const float*)d_in[6];
    const float* four_w = (const float*)d_in[7];
    const float* w_w    = (const float*)d_in[8];
    const float* w_b    = (const float*)d_in[9];
    const float* ln_s   = (const float*)d_in[10];
    const float* ln_b   = (const float*)d_in[11];
    const float* lin_w  = (const float*)d_in[12];
    const float* lin_b  = (const float*)d_in[13];
    const float* ew_w   = (const float*)d_in[14];
    const float* ew_b   = (const float*)d_in[15];
    const float* g1_w   = (const float*)d_in[16];
    const float* g1_b   = (const float*)d_in[17];
    const float* g2_w   = (const float*)d_in[18];
    const float* g2_b   = (const float*)d_in[19];
    const float* proj_w = (const float*)d_in[20];
    const float* proj_b = (const float*)d_in[21];
    const float* q1_w   = (const float*)d_in[22];
    const float* q1_b   = (const float*)d_in[23];
    const float* q2_w   = (const float*)d_in[24];
    const float* q2_b   = (const float*)d_in[25];

    char* wsb = (char*)d_ws;
    size_t off = 0;
    auto alloc = [&](size_t bytes) -> void* {
        void* p = wsb + off; off += (bytes + 255) & ~(size_t)255; return p;
    };
    float* xft_part  = (float*)alloc((size_t)B_ * KS_ * 65536 * 4);
    float* xftT      = (float*)alloc((size_t)B_ * 65536 * 4);
    unsigned short* h_bf   = (unsigned short*)alloc((size_t)BN * W_ * 2);
    unsigned short* hT_bf  = (unsigned short*)alloc((size_t)BN * W_ * 2);
    unsigned short* U_bf   = (unsigned short*)alloc((size_t)BN * NF_ * 2);
    unsigned short* UT_bf  = (unsigned short*)alloc((size_t)BN * NF_ * 2);
    unsigned short* xfg    = (unsigned short*)alloc((size_t)BN * W_ * 2);
    unsigned short* xf_bf  = (unsigned short*)alloc((size_t)BN * W_ * 2);
    unsigned short* xs_bf  = (unsigned short*)alloc((size_t)BN * W_ * 2);
    unsigned short* xsn_bf = (unsigned short*)alloc((size_t)BN * W_ * 2);
    unsigned short* oftT_bf= (unsigned short*)alloc((size_t)B_ * 65536 * 2);
    unsigned short* wwb    = (unsigned short*)alloc((size_t)L_ * W_ * W_ * 2);
    unsigned short* linwb  = (unsigned short*)alloc((size_t)L_ * W_ * W_ * 2);
    unsigned short* projwb = (unsigned short*)alloc((size_t)W_ * 2 * W_ * 2);
    unsigned short* q1wb   = (unsigned short*)alloc((size_t)128 * W_ * 2);
    int*   srcp    = (int*)alloc((size_t)E_ * 4);
    float* ewt_p   = (float*)alloc((size_t)E_ * 4);
    int*   count   = (int*)alloc((size_t)BN * 4);
    int*   cursor  = (int*)alloc((size_t)BN * 4);
    int*   offsets = (int*)alloc((size_t)(BN + 1) * 4);

    // ---- CSR build ----
    hipMemsetAsync(count, 0, (size_t)2 * BN * 4, stream);
    k_hist<<<E_/256, 256, 0, stream>>>(ei, count);
    k_scan<<<1, 1024, 0, stream>>>(count, offsets);
    k_place<<<E_/256, 256, 0, stream>>>(ei, ewt, offsets, cursor, srcp, ewt_p);

    // ---- fused prologue ----
    k_prologue<<<4768, 256, 0, stream>>>(
        w_w, lin_w, proj_w, q1_w, wwb, linwb, projwb, q1wb,
        U, UT_bf, U_bf,
        x, p_w, p_b, h_bf, hT_bf);

    for (int l = 0; l < L_; ++l) {
        // spectral split-K (needs hT) || xs GEMM (needs h only)
        k_spec_xs<<<768, 256, 0, stream>>>(
            hT_bf, UT_bf, xft_part,
            h_bf, linwb + (long)l*W_*W_, lin_b + l*W_, xs_bf);
        k_reduce_ks<<<(B_*65536)/256, 256, 0, stream>>>(xft_part, xftT);
        // fourier (HBM weight stream) || gate_agg (cache gather; long pole)
        k_four_gate<<<256 + BN/4, 256, 0, stream>>>(
            four_w + (long)l*W_*W_*NF_, xftT, oftT_bf,
            offsets, srcp, ewt_p, lif,
            ew_w + l*16, ew_b + l*16, g1_w + l*144, g1_b + l*3,
            g2_w + l*3, g2_b + l, xs_bf, xsn_bf);
        // xf = U·oftT^T + h·ww^T  (bf16 out)
        k_mfma_nt<true,1,false><<<dim3(2, N_/128, B_), 256, 0, stream>>>(
            U_bf, NF_, (long)N_*NF_, 0,
            oftT_bf, NF_, (long)65536, 0, NF_,
            h_bf, W_, (long)N_*W_,
            wwb + (long)l*W_*W_, W_, 0, W_,
            xfg, W_, (long)N_*W_, 0,
            nullptr, nullptr, nullptr, nullptr, nullptr, 1);
        k_gelu_ln<<<BN/4, 256, 0, stream>>>(xfg, xf_bf, w_b + l*W_, ln_s + l*W_, ln_b + l*W_);
        // h = xf_bf @ projW1^T + xsn @ projW2^T + proj_b; l<3 also emits hT via TROUT
        if (l < 3) {
            k_mfma_nt<true,1,true,false,true><<<dim3(2, BN/128, 1), 256, 0, stream>>>(
                xf_bf, W_, 0, 0,
                projwb, 2*W_, 0, 0, W_,
                xsn_bf, W_, 0,
                projwb + W_, 2*W_, 0, W_,
                h_bf, W_, 0, 0,
                hT_bf, proj_b, nullptr, nullptr, nullptr, 1);
        } else {
            k_mfma_nt<true,1,true><<<dim3(2, BN/128, 1), 256, 0, stream>>>(
                xf_bf, W_, 0, 0,
                projwb, 2*W_, 0, 0, W_,
                xsn_bf, W_, 0,
                projwb + W_, 2*W_, 0, W_,
                h_bf, W_, 0, 0,
                nullptr, proj_b, nullptr, nullptr, nullptr, 1);
        }
    }
    // fused q-head
    k_mfma_nt<false,0,true,true><<<dim3(1, BN/128, 1), 256, 0, stream>>>(
        h_bf, W_, 0, 0,
        q1wb, W_, 0, 0, W_,
        nullptr, 0, 0, nullptr, 0, 0, 0,
        nullptr, 128, 0, 0,
        nullptr, q1_b, q2_w, q2_b, (float*)d_out, 1);
}